// Round 5
// baseline (882.409 us; speedup 1.0000x reference)
//
#include <hip/hip_runtime.h>
#include <stdint.h>

// native 4-float vector (same layout as float4), valid for vector builtins
typedef float floatx4 __attribute__((ext_vector_type(4)));

// ---------------------------------------------------------------------------
// Host copy of exact JAX Threefry-2x32 (jax/_src/prng.py; Random123 constants)
// used only to derive rkey = fold_in(key(42), 0) on the host.
// ---------------------------------------------------------------------------
static inline void threefry2x32_host(uint32_t k0, uint32_t k1,
                                     uint32_t x0, uint32_t x1,
                                     uint32_t& o0, uint32_t& o1) {
  const uint32_t ks2 = k0 ^ k1 ^ 0x1BD11BDAu;
#define TF_ROUND(r) { x0 += x1; x1 = (x1 << (r)) | (x1 >> (32 - (r))); x1 ^= x0; }
  x0 += k0; x1 += k1;
  TF_ROUND(13) TF_ROUND(15) TF_ROUND(26) TF_ROUND(6)
  x0 += k1;  x1 += ks2 + 1u;
  TF_ROUND(17) TF_ROUND(29) TF_ROUND(16) TF_ROUND(24)
  x0 += ks2; x1 += k0 + 2u;
  TF_ROUND(13) TF_ROUND(15) TF_ROUND(26) TF_ROUND(6)
  x0 += k0;  x1 += k1 + 3u;
  TF_ROUND(17) TF_ROUND(29) TF_ROUND(16) TF_ROUND(24)
  x0 += k1;  x1 += ks2 + 4u;
  TF_ROUND(13) TF_ROUND(15) TF_ROUND(26) TF_ROUND(6)
  x0 += ks2; x1 += k0 + 5u;
#undef TF_ROUND
  o0 = x0; o1 = x1;
}

// ---------------------------------------------------------------------------
// Device: jax partitionable 32-bit draw for counter ctr (< 2^32).
// Caller passes x1 = ctr + k1 (initial key add strength-reduced); x0 = k0.
// Rotates via __builtin_rotateleft32 -> v_alignbit_b32.
// 20*(add,alignbit,xor) + 10 injection adds + final xor ~= 71 VALU ops.
// ---------------------------------------------------------------------------
__device__ __forceinline__ uint32_t tf_bits(uint32_t x1, uint32_t k0,
                                            uint32_t k1, uint32_t ks2) {
  uint32_t x0 = k0;
#define R4(a,b,c,d)                                              \
  x0 += x1; x1 = __builtin_rotateleft32(x1, a); x1 ^= x0;        \
  x0 += x1; x1 = __builtin_rotateleft32(x1, b); x1 ^= x0;        \
  x0 += x1; x1 = __builtin_rotateleft32(x1, c); x1 ^= x0;        \
  x0 += x1; x1 = __builtin_rotateleft32(x1, d); x1 ^= x0;
  R4(13, 15, 26, 6)
  x0 += k1;  x1 += ks2 + 1u;
  R4(17, 29, 16, 24)
  x0 += ks2; x1 += k0 + 2u;
  R4(13, 15, 26, 6)
  x0 += k0;  x1 += k1 + 3u;
  R4(17, 29, 16, 24)
  x0 += k1;  x1 += ks2 + 4u;
  R4(13, 15, 26, 6)
  x0 += ks2; x1 += k0 + 5u;
#undef R4
  return x0 ^ x1;  // bits = o0 ^ o1 (partitionable stream)
}

// quantize one value, bit-exact vs JAX:
//   r = bitcast((bits>>9)|0x3f800000) - 1
//   temp = floor(v*inv_sigma + r) * sigma   (v*inv_sigma exact pow-2 -> fma ok)
//   clip(temp, tmin, tmax)
__device__ __forceinline__ float qround(float v, uint32_t bits, float sigma,
                                        float inv_sigma, float tmin, float tmax) {
  float r = __uint_as_float((bits >> 9) | 0x3f800000u) - 1.0f;
  float t = floorf(__builtin_fmaf(v, inv_sigma, r)) * sigma;
  return fminf(fmaxf(t, tmin), tmax);
}

// ---------------------------------------------------------------------------
// Fused kernel: ONE pass over x, 8 elements/thread (two adjacent float4s).
//  - counts at sigma0 thresholds via coarse min/max filter: a wave runs the
//    32 exact compares only if some element exceeds the tightest threshold
//    (never, for sane data). Exact for ANY input.
//  - output quantized speculatively with sigma_spec = 0.125 (the value the
//    reference picks whenever underflow < 1%). fixup_kernel repairs on
//    mispredict.
//  - 8 independent threefry chains/thread -> enough ILP to saturate the
//    in-order VALU issue; 2 loads in flight at wave start.
// ---------------------------------------------------------------------------
__global__ __launch_bounds__(256) void fused_kernel(
    const float4* __restrict__ x4, floatx4* __restrict__ o4,
    const float* __restrict__ x, float* __restrict__ out,
    long long n8, long long n, unsigned int* __restrict__ counts,
    uint32_t k0, uint32_t k1) {
  const uint32_t ks2 = k0 ^ k1 ^ 0x1BD11BDAu;   // uniform -> SALU
  // speculative quant params (sigma = 0.125)
  const float sigma = 0.125f, inv_sigma = 8.0f;
  const float tmax = 15.875f, tmin = -16.0f;
  // sigma0 = 0.25 count thresholds (reference constants)
  const float ctmax = 31.75f, ctmin = -32.0f;
  const float chtmax = 15.875f, chtmin = -16.0f;

  long long i = (long long)blockIdx.x * 256 + threadIdx.x;
  unsigned int over = 0, under = 0;
  if (i < n8) {
    float4 va = x4[2 * i];
    float4 vb = x4[2 * i + 1];

    // coarse filter: max/min trees (v_max3/v_min3) + one wave-uniform test
    float mx = fmaxf(fmaxf(fmaxf(va.x, va.y), fmaxf(va.z, va.w)),
                     fmaxf(fmaxf(vb.x, vb.y), fmaxf(vb.z, vb.w)));
    float mn = fminf(fminf(fminf(va.x, va.y), fminf(va.z, va.w)),
                     fminf(fminf(vb.x, vb.y), fminf(vb.z, vb.w)));
    if (__any(mx > chtmax || mn < chtmin)) {
      // exact counts (rare path; disjoint predicates so sum == reference)
      over  = __popcll(__ballot(va.x > ctmax))  + __popcll(__ballot(va.x < ctmin))
            + __popcll(__ballot(va.y > ctmax))  + __popcll(__ballot(va.y < ctmin))
            + __popcll(__ballot(va.z > ctmax))  + __popcll(__ballot(va.z < ctmin))
            + __popcll(__ballot(va.w > ctmax))  + __popcll(__ballot(va.w < ctmin))
            + __popcll(__ballot(vb.x > ctmax))  + __popcll(__ballot(vb.x < ctmin))
            + __popcll(__ballot(vb.y > ctmax))  + __popcll(__ballot(vb.y < ctmin))
            + __popcll(__ballot(vb.z > ctmax))  + __popcll(__ballot(vb.z < ctmin))
            + __popcll(__ballot(vb.w > ctmax))  + __popcll(__ballot(vb.w < ctmin));
      under = __popcll(__ballot(va.x > chtmax)) + __popcll(__ballot(va.x < chtmin))
            + __popcll(__ballot(va.y > chtmax)) + __popcll(__ballot(va.y < chtmin))
            + __popcll(__ballot(va.z > chtmax)) + __popcll(__ballot(va.z < chtmin))
            + __popcll(__ballot(va.w > chtmax)) + __popcll(__ballot(va.w < chtmin))
            + __popcll(__ballot(vb.x > chtmax)) + __popcll(__ballot(vb.x < chtmin))
            + __popcll(__ballot(vb.y > chtmax)) + __popcll(__ballot(vb.y < chtmin))
            + __popcll(__ballot(vb.z > chtmax)) + __popcll(__ballot(vb.z < chtmin))
            + __popcll(__ballot(vb.w > chtmax)) + __popcll(__ballot(vb.w < chtmin));
    }

    // 8 independent threefry chains (counters 8i .. 8i+7)
    uint32_t s = ((uint32_t)i << 3) + k1;        // ctr + k1, one v_lshl_add
    uint32_t b0 = tf_bits(s + 0u, k0, k1, ks2);
    uint32_t b1 = tf_bits(s + 1u, k0, k1, ks2);
    uint32_t b2 = tf_bits(s + 2u, k0, k1, ks2);
    uint32_t b3 = tf_bits(s + 3u, k0, k1, ks2);
    uint32_t b4 = tf_bits(s + 4u, k0, k1, ks2);
    uint32_t b5 = tf_bits(s + 5u, k0, k1, ks2);
    uint32_t b6 = tf_bits(s + 6u, k0, k1, ks2);
    uint32_t b7 = tf_bits(s + 7u, k0, k1, ks2);

    floatx4 ra, rb;
    ra.x = qround(va.x, b0, sigma, inv_sigma, tmin, tmax);
    ra.y = qround(va.y, b1, sigma, inv_sigma, tmin, tmax);
    ra.z = qround(va.z, b2, sigma, inv_sigma, tmin, tmax);
    ra.w = qround(va.w, b3, sigma, inv_sigma, tmin, tmax);
    rb.x = qround(vb.x, b4, sigma, inv_sigma, tmin, tmax);
    rb.y = qround(vb.y, b5, sigma, inv_sigma, tmin, tmax);
    rb.z = qround(vb.z, b6, sigma, inv_sigma, tmin, tmax);
    rb.w = qround(vb.w, b7, sigma, inv_sigma, tmin, tmax);
    o4[2 * i]     = ra;
    o4[2 * i + 1] = rb;
  }
  // lane 0 active iff any lane of the wave was active (smallest i in wave)
  if ((threadIdx.x & 63) == 0) {
    if (over)  atomicAdd(&counts[0], over);
    if (under) atomicAdd(&counts[1], under);
  }
  // generic scalar tail (n % 8 != 0) -- dead for n = 2^27
  if (i == 0 && (n & 7)) {
    unsigned int o2 = 0, u2 = 0;
    for (long long j = n8 << 3; j < n; ++j) {
      float v = x[j];
      o2 += (v > ctmax)  + (v < ctmin);
      u2 += (v > chtmax) + (v < chtmin);
      uint32_t b = tf_bits((uint32_t)j + k1, k0, k1, ks2);
      out[j] = qround(v, b, sigma, inv_sigma, tmin, tmax);
    }
    if (o2) atomicAdd(&counts[0], o2);
    if (u2) atomicAdd(&counts[1], u2);
  }
}

// ---------------------------------------------------------------------------
// Fixup: derive true sigma from global counts; if the 0.125 speculation held
// (always, for well-scaled data) every wg exits after two uniform scalar
// loads. Otherwise recompute the whole output with the true sigma.
// ---------------------------------------------------------------------------
__global__ __launch_bounds__(256) void fixup_kernel(
    const float4* __restrict__ x4, floatx4* __restrict__ o4,
    const float* __restrict__ x, float* __restrict__ out,
    long long n4, long long n, const unsigned int* __restrict__ counts,
    float inv_n, uint32_t k0, uint32_t k1) {
  float overflow  = (float)counts[0] * inv_n;    // exact: inv_n = 2^-27
  float underflow = (float)counts[1] * inv_n;
  // sigma = where(over > .01, 2s, where(under < .01, s/2, s)), s = 0.25
  float sigma = (overflow > 0.01f) ? 0.5f
              : ((underflow < 0.01f) ? 0.125f : 0.25f);
  if (sigma == 0.125f) return;                   // speculation held
  float tmax = sigma * 128.0f - sigma;
  float tmin = sigma * -128.0f;
  float inv_sigma = 1.0f / sigma;                // exact pow-2
  const uint32_t ks2 = k0 ^ k1 ^ 0x1BD11BDAu;

  long long idx = (long long)blockIdx.x * 256 + threadIdx.x;
  long long stride = (long long)gridDim.x * 256;
  for (long long i = idx; i < n4; i += stride) {
    float4 v = x4[i];
    uint32_t s = ((uint32_t)i << 2) + k1;
    uint32_t b0 = tf_bits(s + 0u, k0, k1, ks2);
    uint32_t b1 = tf_bits(s + 1u, k0, k1, ks2);
    uint32_t b2 = tf_bits(s + 2u, k0, k1, ks2);
    uint32_t b3 = tf_bits(s + 3u, k0, k1, ks2);
    floatx4 r;
    r.x = qround(v.x, b0, sigma, inv_sigma, tmin, tmax);
    r.y = qround(v.y, b1, sigma, inv_sigma, tmin, tmax);
    r.z = qround(v.z, b2, sigma, inv_sigma, tmin, tmax);
    r.w = qround(v.w, b3, sigma, inv_sigma, tmin, tmax);
    o4[i] = r;
  }
  if (idx == 0 && (n & 3)) {
    for (long long j = n4 << 2; j < n; ++j) {
      uint32_t b = tf_bits((uint32_t)j + k1, k0, k1, ks2);
      out[j] = qround(x[j], b, sigma, inv_sigma, tmin, tmax);
    }
  }
}

extern "C" void kernel_launch(void* const* d_in, const int* in_sizes, int n_in,
                              void* d_out, int out_size, void* d_ws, size_t ws_size,
                              hipStream_t stream) {
  const float* x = (const float*)d_in[0];
  float* out = (float*)d_out;
  long long n = (long long)in_sizes[0];   // 134217728 = 2^27 elements

  unsigned int* counts = (unsigned int*)d_ws;
  (void)hipMemsetAsync(counts, 0, 2 * sizeof(unsigned int), stream);

  // rkey = fold_in(key(42), 0) = threefry((0,42), (0,0)) -- config-independent
  uint32_t k0, k1;
  threefry2x32_host(0u, 42u, 0u, 0u, k0, k1);

  long long n8 = n >> 3;
  long long grid = (n8 + 255) / 256;
  if (grid < 1) grid = 1;                 // thread 0 must exist (tail)

  fused_kernel<<<(dim3)(unsigned)grid, 256, 0, stream>>>(
      (const float4*)x, (floatx4*)out, x, out, n8, n, counts, k0, k1);

  float inv_n = 1.0f / (float)n;
  long long n4 = n >> 2;
  long long gridf = (n4 + 255) / 256;
  if (gridf < 1) gridf = 1;
  if (gridf > 2048) gridf = 2048;         // early-exit cheap; loop on mispredict
  fixup_kernel<<<(dim3)(unsigned)gridf, 256, 0, stream>>>(
      (const float4*)x, (floatx4*)out, x, out, n4, n, counts, inv_n, k0, k1);
}